// Round 17
// baseline (63.896 us; speedup 1.0000x reference)
//
#include <hip/hip_runtime.h>
#include <hip/hip_bf16.h>
#include <math.h>

#define CIN 256
#define COUT 768   // 3 * OUTC
#define OUTC 256
#define HH 64
#define WW 64
#define HW 4096

typedef unsigned int uint32;
typedef unsigned short ushort16;
typedef unsigned long long u64;

using short8 = __attribute__((ext_vector_type(8))) short;
using f32x4  = __attribute__((ext_vector_type(4))) float;
using hf8    = __attribute__((ext_vector_type(8))) _Float16;

__device__ inline uint32 pkbf2(float a, float b) {
    __hip_bfloat162 h = __float22bfloat162_rn(make_float2(a, b));
    union { __hip_bfloat162 h2; uint32 u; } cv; cv.h2 = h;
    return cv.u;
}
__device__ inline uint32 pkhf2(float a, float b) {
    union { _Float16 h[2]; uint32 u; } cv;
    cv.h[0] = (_Float16)a; cv.h[1] = (_Float16)b;
    return cv.u;
}

// ---------------------------------------------------------------------------
// Kernel 1 (v7): QKV projection (EXACT R14 body, ~21.9 us).
// Output: qkv_f16[n][slot=d>>5][p][dlow=d&31]
// ---------------------------------------------------------------------------
#define LDSTR 40   // shorts per LDS row (32 + 8 pad)

__global__ __launch_bounds__(256) void qkv_gemm_kernel(
    const float* __restrict__ x, const float* __restrict__ wq,
    const float* __restrict__ bq, ushort16* __restrict__ qkv)
{
    __shared__ __align__(16) char smem[32768];
    ushort16* As = (ushort16*)smem;            // [128][LDSTR]
    ushort16* Bs = (ushort16*)smem + 128 * LDSTR;

    const int n   = blockIdx.z;
    const int d0  = blockIdx.y * 128;
    const int p0  = blockIdx.x * 128;
    const int tid = threadIdx.x;
    const int lane = tid & 63;
    const int wid  = tid >> 6;
    const int wm = wid >> 1;
    const int wn = wid & 1;

    const float* xb = x + (size_t)n * CIN * HW;

    const int arow = tid >> 2;
    const int akk  = (tid & 3) * 8;
    const float* aptr = wq + (size_t)(d0 + arow) * CIN + akk;
    const int bkg = (tid >> 6) * 8;
    const int bpg = (tid & 63) * 2;
    const float* bptr = xb + (size_t)bkg * HW + p0 + bpg;

    ushort16* awr0 = &As[arow * LDSTR + akk];
    ushort16* awr1 = &As[(arow + 64) * LDSTR + akk];
    ushort16* bwr0 = &Bs[bpg * LDSTR + bkg];
    ushort16* bwr1 = &Bs[(bpg + 1) * LDSTR + bkg];

    f32x4 acc[4][4];
    #pragma unroll
    for (int i = 0; i < 4; ++i)
        #pragma unroll
        for (int j = 0; j < 4; ++j) acc[i][j] = (f32x4){0.f, 0.f, 0.f, 0.f};

    const int lrow = lane & 15;
    const int lk   = (lane >> 4) * 8;

    float4 a0[4], a1[4];
    float2 b0[8], b1[8];

#define LOAD_SET(aS, bS, ko) do {                                         \
        aS[0] = *(const float4*)(aptr + (ko));                            \
        aS[1] = *(const float4*)(aptr + (ko) + 4);                        \
        aS[2] = *(const float4*)(aptr + (size_t)64 * CIN + (ko));         \
        aS[3] = *(const float4*)(aptr + (size_t)64 * CIN + (ko) + 4);     \
        _Pragma("unroll")                                                 \
        for (int j = 0; j < 8; ++j)                                       \
            bS[j] = *(const float2*)(bptr + (size_t)((ko) + j) * HW);     \
    } while (0)

#define WRITE_SET(aS, bS) do {                                            \
        uint32 w0 = pkbf2(aS[0].x, aS[0].y), w1 = pkbf2(aS[0].z, aS[0].w);\
        uint32 w2 = pkbf2(aS[1].x, aS[1].y), w3 = pkbf2(aS[1].z, aS[1].w);\
        *(uint4*)awr0 = make_uint4(w0, w1, w2, w3);                       \
        w0 = pkbf2(aS[2].x, aS[2].y); w1 = pkbf2(aS[2].z, aS[2].w);       \
        w2 = pkbf2(aS[3].x, aS[3].y); w3 = pkbf2(aS[3].z, aS[3].w);       \
        *(uint4*)awr1 = make_uint4(w0, w1, w2, w3);                       \
        uint4 c0, c1;                                                     \
        c0.x = pkbf2(bS[0].x, bS[1].x); c0.y = pkbf2(bS[2].x, bS[3].x);   \
        c0.z = pkbf2(bS[4].x, bS[5].x); c0.w = pkbf2(bS[6].x, bS[7].x);   \
        c1.x = pkbf2(bS[0].y, bS[1].y); c1.y = pkbf2(bS[2].y, bS[3].y);   \
        c1.z = pkbf2(bS[4].y, bS[5].y); c1.w = pkbf2(bS[6].y, bS[7].y);   \
        *(uint4*)bwr0 = c0;                                               \
        *(uint4*)bwr1 = c1;                                               \
    } while (0)

#define COMPUTE() do {                                                    \
        short8 af[4], bf[4];                                              \
        _Pragma("unroll")                                                 \
        for (int fm = 0; fm < 4; ++fm)                                    \
            af[fm] = *(const short8*)&As[(wm * 64 + fm * 16 + lrow) * LDSTR + lk]; \
        _Pragma("unroll")                                                 \
        for (int fn = 0; fn < 4; ++fn)                                    \
            bf[fn] = *(const short8*)&Bs[(wn * 64 + fn * 16 + lrow) * LDSTR + lk]; \
        _Pragma("unroll")                                                 \
        for (int fm = 0; fm < 4; ++fm)                                    \
            _Pragma("unroll")                                             \
            for (int fn = 0; fn < 4; ++fn)                                \
                acc[fm][fn] = __builtin_amdgcn_mfma_f32_16x16x32_bf16(    \
                    af[fm], bf[fn], acc[fm][fn], 0, 0, 0);                \
    } while (0)

    LOAD_SET(a0, b0, 0);
    LOAD_SET(a1, b1, 32);

    #pragma unroll 1
    for (int kt = 0; kt < 8; kt += 2) {
        __syncthreads();
        WRITE_SET(a0, b0);
        if (kt + 2 < 8) LOAD_SET(a0, b0, (kt + 2) * 32);
        __syncthreads();
        COMPUTE();

        __syncthreads();
        WRITE_SET(a1, b1);
        if (kt + 3 < 8) LOAD_SET(a1, b1, (kt + 3) * 32);
        __syncthreads();
        COMPUTE();
    }
#undef LOAD_SET
#undef WRITE_SET
#undef COMPUTE

    __syncthreads();

    u64* E = (u64*)smem + (size_t)wid * 1024;

    const int hi4 = lane >> 4;
    #pragma unroll
    for (int fm = 0; fm < 4; ++fm) {
        const int D = d0 + wm * 64 + fm * 16 + hi4 * 4;
        const float4 bias = *(const float4*)(&bq[D]);
        const int cell = fm * 2 + (hi4 >> 1);
        const int half = hi4 & 1;
        #pragma unroll
        for (int fn = 0; fn < 4; ++fn) {
            const int pl = fn * 16 + lrow;
            f32x4 v = acc[fm][fn];
            u64 pk = (u64)pkhf2(v[0] + bias.x, v[1] + bias.y)
                   | ((u64)pkhf2(v[2] + bias.z, v[3] + bias.w) << 32);
            E[pl * 16 + (cell ^ (pl & 7)) * 2 + half] = pk;
        }
    }
    const int pl4 = lane >> 2;
    const int dq  = lane & 3;
    ushort16* qn = qkv + (size_t)n * COUT * HW;
    #pragma unroll
    for (int s = 0; s < 2; ++s) {
        const int D = d0 + wm * 64 + s * 32;
        const int slot = D >> 5;
        ushort16* sb2 = qn + (size_t)slot * (HW * 32);
        #pragma unroll
        for (int g = 0; g < 4; ++g) {
            const int prow = g * 16 + pl4;
            const int c = s * 4 + dq;
            const uint4 val = *(const uint4*)&E[prow * 16 + ((c ^ (prow & 7)) * 2)];
            *(uint4*)(sb2 + (size_t)(p0 + wn * 64 + prow) * 32 + dq * 8) = val;
        }
    }
}

// ---------------------------------------------------------------------------
// Kernel 2 (v10): MFMA neighborhood attention.
// Wave = 4x4 q-block; 8x8 key window (64 px).
// QK: S^T_g = mfma_f32_16x16x32_f16(A=K_group_g, B=Q)  (swapped: lane holds
//     one q's P-row spread over regs -> lane-local softmax + relayout).
// Softmax: 16 in-lane values + shfl_xor(16,32) over the 4 hi-lanes of q.
// PV: P repacked (8 cvt_pk + 16 shfl, algebra verified) -> A-frags;
//     V staged LDS-TRANSPOSED Vt[d][px] (72-f16 padded rows, b128 reads);
//     4 mfma accumulate O in f32.
// Per-wave-private LDS (8.7 KB) -> no barriers. 2048 blocks, 4 waves each.
// ---------------------------------------------------------------------------
__global__ __launch_bounds__(256) void attn_kernel(
    const ushort16* __restrict__ qkv, float* __restrict__ out)
{
    __shared__ uint4 sh[4 * 544];   // per wave: K 256 units + Vt 288 units

    const int n    = blockIdx.z;
    const int head = blockIdx.y;
    const int qby  = blockIdx.x >> 2;     // 0..15
    const int qbxg = blockIdx.x & 3;      // 0..3

    const int tid  = threadIdx.x;
    const int wid  = tid >> 6;
    const int lane = tid & 63;

    const int h0  = qby * 4;
    const int w0q = (qbxg * 4 + wid) * 4;

    uint4* Ksw = sh + wid * 544;          // K:  [px 0..63][4 units, swizzled]
    uint4* Vtw = Ksw + 256;               // Vt: [d 0..31][9 units (72 f16)]
    _Float16* Vt16 = (_Float16*)Vtw;

    const uint4* Qb = (const uint4*)(qkv + ((size_t)(n * 24 + head)) * HW * 32);
    const uint4* Kb = (const uint4*)(qkv + ((size_t)(n * 24 + 8 + head)) * HW * 32);
    const uint4* Vb = (const uint4*)(qkv + ((size_t)(n * 24 + 16 + head)) * HW * 32);

    // ---- stage: lane owns window px = lane ----
    {
        const int wy = lane >> 3, wx = lane & 7;
        const int gh = h0 + wy - 2, gw = w0q + wx - 2;
        const bool inb = (gh >= 0) && (gh < HH) && (gw >= 0) && (gw < WW);
        const size_t gp = inb ? (size_t)(gh * WW + gw) * 4 : 0;
        const uint4 z4 = make_uint4(0u, 0u, 0u, 0u);
        uint4 kv[4];
        union { uint4 v[4]; _Float16 h[32]; } V;
        #pragma unroll
        for (int u = 0; u < 4; ++u) {
            kv[u]  = inb ? Kb[gp + u] : z4;
            V.v[u] = inb ? Vb[gp + u] : z4;
        }
        #pragma unroll
        for (int u = 0; u < 4; ++u)
            Ksw[lane * 4 + (u ^ ((lane >> 1) & 3))] = kv[u];
        #pragma unroll
        for (int d = 0; d < 32; ++d)
            Vt16[d * 72 + lane] = V.h[d];
    }

    const int q  = lane & 15;
    const int hi = lane >> 4;
    const int qy = q >> 2, qx = q & 3;

    // ---- Q B-frag: one global uint4 (q's dims 8*hi..8*hi+7) ----
    union { uint4 u; hf8 h; } Bq;
    Bq.u = Qb[(size_t)((h0 + qy) * WW + (w0q + qx)) * 4 + hi];

    // ---- QK: 4 MFMAs (one per key-px group of 16) ----
    f32x4 S[4];
    #pragma unroll
    for (int g = 0; g < 4; ++g) {
        const int px = g * 16 + q;      // A row = key px
        union { uint4 u; hf8 h; } Ka;
        Ka.u = Ksw[px * 4 + (hi ^ ((px >> 1) & 3))];
        S[g] = __builtin_amdgcn_mfma_f32_16x16x32_f16(
            Ka.h, Bq.h, (f32x4){0.f, 0.f, 0.f, 0.f}, 0, 0, 0);
    }

    // ---- mask + softmax (lane holds P[q][px=16g+4hi+r]) ----
    float e[4][4];
    float mx = -1e30f;
    #pragma unroll
    for (int g = 0; g < 4; ++g)
        #pragma unroll
        for (int r = 0; r < 4; ++r) {
            const int t  = 4 * hi + r;
            const int wy = 2 * g + (t >> 3);
            const int wx = t & 7;
            const bool valid =
                ((unsigned)(wy - qy) <= 4u) && ((unsigned)(wx - qx) <= 4u) &&
                ((unsigned)(h0 + wy - 2) < (unsigned)HH) &&
                ((unsigned)(w0q + wx - 2) < (unsigned)WW);
            const float s = valid ? S[g][r] : -1e30f;
            e[g][r] = s;
            mx = fmaxf(mx, s);
        }
    mx = fmaxf(mx, __shfl_xor(mx, 16, 64));
    mx = fmaxf(mx, __shfl_xor(mx, 32, 64));
    float sum = 0.f;
    #pragma unroll
    for (int g = 0; g < 4; ++g)
        #pragma unroll
        for (int r = 0; r < 4; ++r) {
            const float t = __expf(e[g][r] - mx);
            e[g][r] = t;
            sum += t;
        }
    sum += __shfl_xor(sum, 16, 64);
    sum += __shfl_xor(sum, 32, 64);
    const float inv = 1.f / sum;

    // ---- pack P to f16 pairs: pk[g][pi] = (e[g][2pi], e[g][2pi+1]) ----
    uint32 pk[4][2];
    #pragma unroll
    for (int g = 0; g < 4; ++g) {
        pk[g][0] = pkhf2(e[g][0], e[g][1]);
        pk[g][1] = pkhf2(e[g][2], e[g][3]);
    }

    // ---- PV: relayout P -> A-frags, Vt -> B-frags, 4 MFMAs ----
    f32x4 O[2] = {(f32x4){0.f, 0.f, 0.f, 0.f}, (f32x4){0.f, 0.f, 0.f, 0.f}};
    #pragma unroll
    for (int cc = 0; cc < 2; ++cc) {
        union { uint32 w[4]; hf8 h; } A;
        #pragma unroll
        for (int w = 0; w < 4; ++w) {
            const int b  = w >> 1, pi = w & 1;
            const int sl = q + 16 * ((2 * hi + b) & 3);
            const uint32 lo  = (uint32)__shfl((int)pk[2 * cc][pi],     sl, 64);
            const uint32 hi2 = (uint32)__shfl((int)pk[2 * cc + 1][pi], sl, 64);
            A.w[w] = (hi >= 2) ? hi2 : lo;
        }
        #pragma unroll
        for (int nt = 0; nt < 2; ++nt) {
            union { uint4 u; hf8 h; } Bv;
            Bv.u = *(const uint4*)(Vt16 + (nt * 16 + q) * 72 + cc * 32 + hi * 8);
            O[nt] = __builtin_amdgcn_mfma_f32_16x16x32_f16(
                A.h, Bv.h, O[nt], 0, 0, 0);
        }
    }

    // ---- store: lane holds O[q=(hi*4+r)][d=q+16nt]; scale by that q's inv ----
    float invr[4];
    #pragma unroll
    for (int r = 0; r < 4; ++r)
        invr[r] = __shfl(inv, hi * 4 + r, 64);

    float* Ob = out + (size_t)((n * 8 + head) * 32) * HW;
    #pragma unroll
    for (int r = 0; r < 4; ++r) {
        const int qq = hi * 4 + r;
        const int pp = (h0 + (qq >> 2)) * WW + (w0q + (qq & 3));
        #pragma unroll
        for (int nt = 0; nt < 2; ++nt)
            Ob[(size_t)(nt * 16 + q) * HW + pp] = O[nt][r] * invr[r];
    }
}

// ---------------------------------------------------------------------------
extern "C" void kernel_launch(void* const* d_in, const int* in_sizes, int n_in,
                              void* d_out, int out_size, void* d_ws, size_t ws_size,
                              hipStream_t stream) {
    const float* x  = (const float*)d_in[0];   // (4, 256, 64, 64)
    const float* wq = (const float*)d_in[1];   // (768, 256)
    const float* bq = (const float*)d_in[2];   // (768,)
    float* out = (float*)d_out;                // (4, 256, 64, 64) fp32
    ushort16* qkv = (ushort16*)d_ws;           // fp16 [4][24][4096][32] = 25 MB

    dim3 g1(HW / 128, COUT / 128, 4);          // (32, 6, 4) = 768 blocks
    qkv_gemm_kernel<<<g1, 256, 0, stream>>>(x, wq, bq, qkv);

    dim3 g2(64, 8, 4);                         // (16 qby x 4 qbx-groups, 8, 4)
    attn_kernel<<<g2, 256, 0, stream>>>(qkv, out);
}

// Round 18
// 51.811 us; speedup vs baseline: 1.2333x; 1.2333x over previous
//
#include <hip/hip_runtime.h>
#include <hip/hip_bf16.h>
#include <math.h>

#define CIN 256
#define COUT 768   // 3 * OUTC
#define OUTC 256
#define HH 64
#define WW 64
#define HW 4096

typedef unsigned int uint32;
typedef unsigned short ushort16;
typedef unsigned long long u64;

using short8 = __attribute__((ext_vector_type(8))) short;
using f32x4  = __attribute__((ext_vector_type(4))) float;
using hf2    = __attribute__((ext_vector_type(2))) _Float16;

__device__ inline uint32 pkbf2(float a, float b) {
    __hip_bfloat162 h = __float22bfloat162_rn(make_float2(a, b));
    union { __hip_bfloat162 h2; uint32 u; } cv; cv.h2 = h;
    return cv.u;
}
__device__ inline uint32 pkhf2(float a, float b) {
    union { _Float16 h[2]; uint32 u; } cv;
    cv.h[0] = (_Float16)a; cv.h[1] = (_Float16)b;
    return cv.u;
}
__device__ inline float dpp_xor1(float x) {
#if __has_builtin(__builtin_amdgcn_update_dpp)
    int i = __builtin_amdgcn_update_dpp(0, __float_as_int(x),
                                        0xB1, 0xF, 0xF, true);
    return __int_as_float(i);
#else
    return __shfl_xor(x, 1, 64);
#endif
}
// f32 += dot(h2, h2) — v_dot2_f32_f16 if available, else unpack-fma
__device__ inline float dot2acc(hf2 a, hf2 b, float c) {
#if __has_builtin(__builtin_amdgcn_fdot2)
    return __builtin_amdgcn_fdot2(a, b, c, false);
#else
    c = fmaf((float)a[0], (float)b[0], c);
    return fmaf((float)a[1], (float)b[1], c);
#endif
}

// ---------------------------------------------------------------------------
// Kernel 0: W fp32 -> bf16 (RTNE, identical rounding to previous in-GEMM cvt)
// 768*256/8 = 24576 chunks / 256 = 96 blocks; ~1 us.
// ---------------------------------------------------------------------------
__global__ __launch_bounds__(256) void cvt_w_kernel(
    const float* __restrict__ wq, ushort16* __restrict__ wb)
{
    const int i = (blockIdx.x * 256 + threadIdx.x) * 8;
    float4 a = *(const float4*)&wq[i];
    float4 b = *(const float4*)&wq[i + 4];
    *(uint4*)&wb[i] = make_uint4(pkbf2(a.x, a.y), pkbf2(a.z, a.w),
                                 pkbf2(b.x, b.y), pkbf2(b.z, b.w));
}

// ---------------------------------------------------------------------------
// Kernel 1 (v8): QKV projection. A (=W, bf16, L2-resident 384 KB) is read
// DIRECTLY from global as b128 fragments — never touches LDS. Only B (=x,
// needs fp32->bf16 cvt) stages through LDS, double-buffered -> ONE barrier
// per kt. Per-kt per-wave LDS ops: 12 -> 6; barriers: 17 -> 10.
// Output: qkv_f16[n][slot=d>>5][p][dlow=d&31]  (math identical to R14)
// ---------------------------------------------------------------------------
#define LDSTR 40   // shorts per LDS row (32 + 8 pad)

__global__ __launch_bounds__(256) void qkv_gemm_kernel(
    const float* __restrict__ x, const ushort16* __restrict__ wb,
    const float* __restrict__ bq, ushort16* __restrict__ qkv)
{
    __shared__ __align__(16) char smem[32768];
    ushort16* Bs0 = (ushort16*)smem;                 // [128][LDSTR] buf 0
    ushort16* Bs1 = (ushort16*)smem + 128 * LDSTR;   // buf 1 (20.5 KB total)

    const int n   = blockIdx.z;
    const int d0  = blockIdx.y * 128;
    const int p0  = blockIdx.x * 128;
    const int tid = threadIdx.x;
    const int lane = tid & 63;
    const int wid  = tid >> 6;
    const int wm = wid >> 1;
    const int wn = wid & 1;

    const float* xb = x + (size_t)n * CIN * HW;

    const int lrow = lane & 15;
    const int lk   = (lane >> 4) * 8;

    // A: direct global bf16 fragment pointers (one per fm)
    const ushort16* ap[4];
    #pragma unroll
    for (int fm = 0; fm < 4; ++fm)
        ap[fm] = wb + (size_t)(d0 + wm * 64 + fm * 16 + lrow) * CIN + lk;

    // B staging: thread -> k-group bkg (8 k), pixel pair bpg
    const int bkg = (tid >> 6) * 8;
    const int bpg = (tid & 63) * 2;
    const float* bptr = xb + (size_t)bkg * HW + p0 + bpg;

    f32x4 acc[4][4];
    #pragma unroll
    for (int i = 0; i < 4; ++i)
        #pragma unroll
        for (int j = 0; j < 4; ++j) acc[i][j] = (f32x4){0.f, 0.f, 0.f, 0.f};

    float2 breg[8];

#define LOADB(ko) do {                                                    \
        _Pragma("unroll")                                                 \
        for (int j = 0; j < 8; ++j)                                       \
            breg[j] = *(const float2*)(bptr + (size_t)((ko) + j) * HW);   \
    } while (0)

#define WRITEB(Bsb) do {                                                  \
        uint4 c0, c1;                                                     \
        c0.x = pkbf2(breg[0].x, breg[1].x); c0.y = pkbf2(breg[2].x, breg[3].x); \
        c0.z = pkbf2(breg[4].x, breg[5].x); c0.w = pkbf2(breg[6].x, breg[7].x); \
        c1.x = pkbf2(breg[0].y, breg[1].y); c1.y = pkbf2(breg[2].y, breg[3].y); \
        c1.z = pkbf2(breg[4].y, breg[5].y); c1.w = pkbf2(breg[6].y, breg[7].y); \
        *(uint4*)&(Bsb)[bpg * LDSTR + bkg]       = c0;                    \
        *(uint4*)&(Bsb)[(bpg + 1) * LDSTR + bkg] = c1;                    \
    } while (0)

#define LOADA(dst, ko) do {                                               \
        _Pragma("unroll")                                                 \
        for (int fm = 0; fm < 4; ++fm)                                    \
            dst[fm] = *(const short8*)(ap[fm] + (ko));                    \
    } while (0)

#define COMPUTE(Bsb, afr) do {                                            \
        short8 bf[4];                                                     \
        _Pragma("unroll")                                                 \
        for (int fn = 0; fn < 4; ++fn)                                    \
            bf[fn] = *(const short8*)&(Bsb)[(wn * 64 + fn * 16 + lrow) * LDSTR + lk]; \
        _Pragma("unroll")                                                 \
        for (int fm = 0; fm < 4; ++fm)                                    \
            _Pragma("unroll")                                             \
            for (int fn = 0; fn < 4; ++fn)                                \
                acc[fm][fn] = __builtin_amdgcn_mfma_f32_16x16x32_bf16(    \
                    afr[fm], bf[fn], acc[fm][fn], 0, 0, 0);               \
    } while (0)

    short8 aX[4], aY[4];

    // prologue: B(kt0) -> Bs0; A(kt0) -> aX; B(kt1) -> regs
    LOADB(0);
    LOADA(aX, 0);
    WRITEB(Bs0);
    LOADB(32);
    __syncthreads();               // Bs0 ready

    #pragma unroll 1
    for (int kt = 0; kt < 8; kt += 2) {
        // ---- even kt: frags aX, buffer Bs0 ----
        LOADA(aY, (kt + 1) * 32);             // prefetch A for kt+1
        COMPUTE(Bs0, aX);
        WRITEB(Bs1);                          // B(kt+1) regs -> buf1
        if (kt + 2 < 8) LOADB((kt + 2) * 32); // prefetch B for kt+2
        __syncthreads();                      // Bs1 ready

        // ---- odd kt+1: frags aY, buffer Bs1 ----
        if (kt + 2 < 8) LOADA(aX, (kt + 2) * 32);
        COMPUTE(Bs1, aY);
        if (kt + 2 < 8) WRITEB(Bs0);          // B(kt+2) regs -> buf0
        if (kt + 3 < 8) LOADB((kt + 3) * 32);
        __syncthreads();                      // Bs0 ready
    }
#undef LOADB
#undef WRITEB
#undef LOADA
#undef COMPUTE

    // ---- epilogue: LDS transpose -> coalesced stores (R10/R14) ----
    __syncthreads();

    u64* E = (u64*)smem + (size_t)wid * 1024;

    const int hi4 = lane >> 4;
    #pragma unroll
    for (int fm = 0; fm < 4; ++fm) {
        const int D = d0 + wm * 64 + fm * 16 + hi4 * 4;
        const float4 bias = *(const float4*)(&bq[D]);
        const int cell = fm * 2 + (hi4 >> 1);
        const int half = hi4 & 1;
        #pragma unroll
        for (int fn = 0; fn < 4; ++fn) {
            const int pl = fn * 16 + lrow;
            f32x4 v = acc[fm][fn];
            u64 pk = (u64)pkhf2(v[0] + bias.x, v[1] + bias.y)
                   | ((u64)pkhf2(v[2] + bias.z, v[3] + bias.w) << 32);
            E[pl * 16 + (cell ^ (pl & 7)) * 2 + half] = pk;
        }
    }
    const int pl4 = lane >> 2;
    const int dq  = lane & 3;
    ushort16* qn = qkv + (size_t)n * COUT * HW;
    #pragma unroll
    for (int s = 0; s < 2; ++s) {
        const int D = d0 + wm * 64 + s * 32;
        const int slot = D >> 5;
        ushort16* sb2 = qn + (size_t)slot * (HW * 32);
        #pragma unroll
        for (int g = 0; g < 4; ++g) {
            const int prow = g * 16 + pl4;
            const int c = s * 4 + dq;
            const uint4 val = *(const uint4*)&E[prow * 16 + ((c ^ (prow & 7)) * 2)];
            *(uint4*)(sb2 + (size_t)(p0 + wn * 64 + prow) * 32 + dq * 8) = val;
        }
    }
}

// ---------------------------------------------------------------------------
// Kernel 2: 5x5 neighborhood attention (EXACT R11 v5 body, ~19.6 us).
// LDS-staged K/V, packed math (fdot2 QK, pk_fma PV), DPP combine.
// ---------------------------------------------------------------------------
#define TR 4
#define TC 32
#define HR 8
#define HC 36
#define NPIX (HR*HC)  // 288

__global__ __launch_bounds__(256) void attn_kernel(
    const ushort16* __restrict__ qkv, float* __restrict__ out)
{
    __shared__ uint4 Ks[NPIX * 4];   // 18 KB
    __shared__ uint4 Vs[NPIX * 4];   // 18 KB

    const int n    = blockIdx.z;
    const int head = blockIdx.y;
    const int ht = blockIdx.x >> 1;
    const int wt = blockIdx.x & 1;
    const int h0 = ht * TR;
    const int w0 = wt * TC;

    const int tid  = threadIdx.x;
    const int half = tid & 1;
    const int wc   = (tid >> 1) & 31;
    const int tr   = tid >> 6;

    const int h = h0 + tr, w = w0 + wc;
    const int p = h * WW + w;

    const uint4* Kb = (const uint4*)(qkv + ((size_t)(n * 24 + 8 + head)) * HW * 32);
    const uint4* Vb = (const uint4*)(qkv + ((size_t)(n * 24 + 16 + head)) * HW * 32);

    for (int c = tid; c < 2 * NPIX * 4; c += 256) {
        const int b  = (c >= NPIX * 4);
        const int cc = c - b * NPIX * 4;
        const int pix = cc >> 2, i = cc & 3;
        const int hr = pix / HC, cw = pix - hr * HC;
        const int hh = h0 + hr - 2, ww = w0 + cw - 2;
        if (hh >= 0 && hh < HH && ww >= 0 && ww < WW) {
            const int pp = hh * WW + ww;
            const uint4 v = (b ? Vb : Kb)[(size_t)pp * 4 + i];
            const int unit = (pix * 4 + i) ^ (pix & 7);
            (b ? Vs : Ks)[unit] = v;
        }
    }

    hf2 q[8];
    {
        const uint4* Qp = (const uint4*)(qkv + (((size_t)(n * 24 + head)) * HW + p) * 32);
        union { uint4 u; hf2 h[4]; } c0, c1;
        c0.u = Qp[half * 2];
        c1.u = Qp[half * 2 + 1];
        #pragma unroll
        for (int i = 0; i < 4; ++i) { q[i] = c0.h[i]; q[4 + i] = c1.h[i]; }
    }

    __syncthreads();

    float sc[25];
    #pragma unroll
    for (int ky = 0; ky < 5; ++ky) {
        const int hh = h + ky - 2;
        const int hr = tr + ky;
        #pragma unroll
        for (int kx = 0; kx < 5; ++kx) {
            const int ww = w + kx - 2;
            float s;
            if (hh >= 0 && hh < HH && ww >= 0 && ww < WW) {
                const int pix = hr * HC + (wc + kx);
                const int u0 = (pix * 4 + half * 2)     ^ (pix & 7);
                const int u1 = (pix * 4 + half * 2 + 1) ^ (pix & 7);
                union { uint4 u; hf2 h[4]; } a, b;
                a.u = Ks[u0]; b.u = Ks[u1];
                float t = 0.f;
                t = dot2acc(q[0], a.h[0], t);
                t = dot2acc(q[1], a.h[1], t);
                t = dot2acc(q[2], a.h[2], t);
                t = dot2acc(q[3], a.h[3], t);
                t = dot2acc(q[4], b.h[0], t);
                t = dot2acc(q[5], b.h[1], t);
                t = dot2acc(q[6], b.h[2], t);
                t = dot2acc(q[7], b.h[3], t);
                s = t;
            } else {
                s = -1e30f;
            }
            sc[ky * 5 + kx] = s;
        }
    }
    #pragma unroll
    for (int k = 0; k < 25; ++k) {
        float o = dpp_xor1(sc[k]);
        sc[k] = (sc[k] <= -1e29f) ? sc[k] : sc[k] + o;
    }

    float m = sc[0];
    #pragma unroll
    for (int k = 1; k < 25; ++k) m = fmaxf(m, sc[k]);
    float sum = 0.f;
    #pragma unroll
    for (int k = 0; k < 25; ++k) {
        float e = __expf(sc[k] - m);
        sc[k] = e;
        sum += e;
    }
    const float inv = 1.f / sum;

    hf2 acch[8];
    #pragma unroll
    for (int i = 0; i < 8; ++i) acch[i] = (hf2){(_Float16)0.f, (_Float16)0.f};
    #pragma unroll
    for (int ky = 0; ky < 5; ++ky) {
        const int hh = h + ky - 2;
        if (hh < 0 || hh >= HH) continue;
        const int hr = tr + ky;
        #pragma unroll
        for (int kx = 0; kx < 5; ++kx) {
            const int ww = w + kx - 2;
            if (ww < 0 || ww >= WW) continue;
            const _Float16 af = (_Float16)sc[ky * 5 + kx];
            const hf2 ah = (hf2){af, af};
            const int pix = hr * HC + (wc + kx);
            const int u0 = (pix * 4 + half * 2)     ^ (pix & 7);
            const int u1 = (pix * 4 + half * 2 + 1) ^ (pix & 7);
            union { uint4 u; hf2 h[4]; } xv, yv;
            xv.u = Vs[u0]; yv.u = Vs[u1];
            acch[0] += ah * xv.h[0];
            acch[1] += ah * xv.h[1];
            acch[2] += ah * xv.h[2];
            acch[3] += ah * xv.h[3];
            acch[4] += ah * yv.h[0];
            acch[5] += ah * yv.h[1];
            acch[6] += ah * yv.h[2];
            acch[7] += ah * yv.h[3];
        }
    }

    float* Ob = out + ((size_t)(n * 8 + head) * 32 + half * 16) * HW + p;
    #pragma unroll
    for (int i = 0; i < 8; ++i) {
        Ob[(size_t)(2*i)   * HW] = (float)acch[i][0] * inv;
        Ob[(size_t)(2*i+1) * HW] = (float)acch[i][1] * inv;
    }
}

// ---------------------------------------------------------------------------
extern "C" void kernel_launch(void* const* d_in, const int* in_sizes, int n_in,
                              void* d_out, int out_size, void* d_ws, size_t ws_size,
                              hipStream_t stream) {
    const float* x  = (const float*)d_in[0];   // (4, 256, 64, 64)
    const float* wq = (const float*)d_in[1];   // (768, 256)
    const float* bq = (const float*)d_in[2];   // (768,)
    float* out = (float*)d_out;                // (4, 256, 64, 64) fp32

    ushort16* qkv = (ushort16*)d_ws;                          // 25.2 MB fp16
    ushort16* wbf = (ushort16*)((char*)d_ws + (32u << 20));   // 384 KB bf16 W

    cvt_w_kernel<<<96, 256, 0, stream>>>(wq, wbf);

    dim3 g1(HW / 128, COUT / 128, 4);          // (32, 6, 4) = 768 blocks
    qkv_gemm_kernel<<<g1, 256, 0, stream>>>(x, wbf, bq, qkv);

    dim3 g2(32, 8, 4);
    attn_kernel<<<g2, 256, 0, stream>>>(qkv, out);
}

// Round 19
// 41.510 us; speedup vs baseline: 1.5393x; 1.2482x over previous
//
#include <hip/hip_runtime.h>
#include <hip/hip_bf16.h>
#include <math.h>

#define CIN 256
#define COUT 768   // 3 * OUTC
#define OUTC 256
#define HH 64
#define WW 64
#define HW 4096

typedef unsigned int uint32;
typedef unsigned short ushort16;
typedef unsigned long long u64;

using short8 = __attribute__((ext_vector_type(8))) short;
using f32x4  = __attribute__((ext_vector_type(4))) float;
using hf2    = __attribute__((ext_vector_type(2))) _Float16;

__device__ inline uint32 pkbf2(float a, float b) {
    __hip_bfloat162 h = __float22bfloat162_rn(make_float2(a, b));
    union { __hip_bfloat162 h2; uint32 u; } cv; cv.h2 = h;
    return cv.u;
}
__device__ inline uint32 pkhf2(float a, float b) {
    union { _Float16 h[2]; uint32 u; } cv;
    cv.h[0] = (_Float16)a; cv.h[1] = (_Float16)b;
    return cv.u;
}
__device__ inline float dpp_xor1(float x) {
#if __has_builtin(__builtin_amdgcn_update_dpp)
    int i = __builtin_amdgcn_update_dpp(0, __float_as_int(x),
                                        0xB1, 0xF, 0xF, true);   // quad_perm [1,0,3,2]
    return __int_as_float(i);
#else
    return __shfl_xor(x, 1, 64);
#endif
}
// f32 += dot(h2, h2) — v_dot2_f32_f16 if available, else unpack-fma
__device__ inline float dot2acc(hf2 a, hf2 b, float c) {
#if __has_builtin(__builtin_amdgcn_fdot2)
    return __builtin_amdgcn_fdot2(a, b, c, false);
#else
    c = fmaf((float)a[0], (float)b[0], c);
    return fmaf((float)a[1], (float)b[1], c);
#endif
}

// ---------------------------------------------------------------------------
// Kernel 1 (v7): QKV projection = R11 body + DEPTH-2 register prefetch.
// (Best measured GEMM variant, ~21.9 us. 8 structures tried; all others
// were neutral or regressions — see session ledger.)
// Output: qkv_f16[n][slot=d>>5][p][dlow=d&31]
// ---------------------------------------------------------------------------
#define LDSTR 40   // shorts per LDS row (32 + 8 pad)

__global__ __launch_bounds__(256) void qkv_gemm_kernel(
    const float* __restrict__ x, const float* __restrict__ wq,
    const float* __restrict__ bq, ushort16* __restrict__ qkv)
{
    __shared__ __align__(16) char smem[32768];
    ushort16* As = (ushort16*)smem;            // [128][LDSTR]
    ushort16* Bs = (ushort16*)smem + 128 * LDSTR;

    const int n   = blockIdx.z;
    const int d0  = blockIdx.y * 128;
    const int p0  = blockIdx.x * 128;
    const int tid = threadIdx.x;
    const int lane = tid & 63;
    const int wid  = tid >> 6;
    const int wm = wid >> 1;
    const int wn = wid & 1;

    const float* xb = x + (size_t)n * CIN * HW;

    const int arow = tid >> 2;
    const int akk  = (tid & 3) * 8;
    const float* aptr = wq + (size_t)(d0 + arow) * CIN + akk;
    const int bkg = (tid >> 6) * 8;
    const int bpg = (tid & 63) * 2;
    const float* bptr = xb + (size_t)bkg * HW + p0 + bpg;

    ushort16* awr0 = &As[arow * LDSTR + akk];
    ushort16* awr1 = &As[(arow + 64) * LDSTR + akk];
    ushort16* bwr0 = &Bs[bpg * LDSTR + bkg];
    ushort16* bwr1 = &Bs[(bpg + 1) * LDSTR + bkg];

    f32x4 acc[4][4];
    #pragma unroll
    for (int i = 0; i < 4; ++i)
        #pragma unroll
        for (int j = 0; j < 4; ++j) acc[i][j] = (f32x4){0.f, 0.f, 0.f, 0.f};

    const int lrow = lane & 15;
    const int lk   = (lane >> 4) * 8;

    float4 a0[4], a1[4];
    float2 b0[8], b1[8];

#define LOAD_SET(aS, bS, ko) do {                                         \
        aS[0] = *(const float4*)(aptr + (ko));                            \
        aS[1] = *(const float4*)(aptr + (ko) + 4);                        \
        aS[2] = *(const float4*)(aptr + (size_t)64 * CIN + (ko));         \
        aS[3] = *(const float4*)(aptr + (size_t)64 * CIN + (ko) + 4);     \
        _Pragma("unroll")                                                 \
        for (int j = 0; j < 8; ++j)                                       \
            bS[j] = *(const float2*)(bptr + (size_t)((ko) + j) * HW);     \
    } while (0)

#define WRITE_SET(aS, bS) do {                                            \
        uint32 w0 = pkbf2(aS[0].x, aS[0].y), w1 = pkbf2(aS[0].z, aS[0].w);\
        uint32 w2 = pkbf2(aS[1].x, aS[1].y), w3 = pkbf2(aS[1].z, aS[1].w);\
        *(uint4*)awr0 = make_uint4(w0, w1, w2, w3);                       \
        w0 = pkbf2(aS[2].x, aS[2].y); w1 = pkbf2(aS[2].z, aS[2].w);       \
        w2 = pkbf2(aS[3].x, aS[3].y); w3 = pkbf2(aS[3].z, aS[3].w);       \
        *(uint4*)awr1 = make_uint4(w0, w1, w2, w3);                       \
        uint4 c0, c1;                                                     \
        c0.x = pkbf2(bS[0].x, bS[1].x); c0.y = pkbf2(bS[2].x, bS[3].x);   \
        c0.z = pkbf2(bS[4].x, bS[5].x); c0.w = pkbf2(bS[6].x, bS[7].x);   \
        c1.x = pkbf2(bS[0].y, bS[1].y); c1.y = pkbf2(bS[2].y, bS[3].y);   \
        c1.z = pkbf2(bS[4].y, bS[5].y); c1.w = pkbf2(bS[6].y, bS[7].y);   \
        *(uint4*)bwr0 = c0;                                               \
        *(uint4*)bwr1 = c1;                                               \
    } while (0)

#define COMPUTE() do {                                                    \
        short8 af[4], bf[4];                                              \
        _Pragma("unroll")                                                 \
        for (int fm = 0; fm < 4; ++fm)                                    \
            af[fm] = *(const short8*)&As[(wm * 64 + fm * 16 + lrow) * LDSTR + lk]; \
        _Pragma("unroll")                                                 \
        for (int fn = 0; fn < 4; ++fn)                                    \
            bf[fn] = *(const short8*)&Bs[(wn * 64 + fn * 16 + lrow) * LDSTR + lk]; \
        _Pragma("unroll")                                                 \
        for (int fm = 0; fm < 4; ++fm)                                    \
            _Pragma("unroll")                                             \
            for (int fn = 0; fn < 4; ++fn)                                \
                acc[fm][fn] = __builtin_amdgcn_mfma_f32_16x16x32_bf16(    \
                    af[fm], bf[fn], acc[fm][fn], 0, 0, 0);                \
    } while (0)

    LOAD_SET(a0, b0, 0);
    LOAD_SET(a1, b1, 32);

    #pragma unroll 1
    for (int kt = 0; kt < 8; kt += 2) {
        __syncthreads();
        WRITE_SET(a0, b0);
        if (kt + 2 < 8) LOAD_SET(a0, b0, (kt + 2) * 32);
        __syncthreads();
        COMPUTE();

        __syncthreads();
        WRITE_SET(a1, b1);
        if (kt + 3 < 8) LOAD_SET(a1, b1, (kt + 3) * 32);
        __syncthreads();
        COMPUTE();
    }
#undef LOAD_SET
#undef WRITE_SET
#undef COMPUTE

    __syncthreads();

    u64* E = (u64*)smem + (size_t)wid * 1024;

    const int hi4 = lane >> 4;
    #pragma unroll
    for (int fm = 0; fm < 4; ++fm) {
        const int D = d0 + wm * 64 + fm * 16 + hi4 * 4;
        const float4 bias = *(const float4*)(&bq[D]);
        const int cell = fm * 2 + (hi4 >> 1);
        const int half = hi4 & 1;
        #pragma unroll
        for (int fn = 0; fn < 4; ++fn) {
            const int pl = fn * 16 + lrow;
            f32x4 v = acc[fm][fn];
            u64 pk = (u64)pkhf2(v[0] + bias.x, v[1] + bias.y)
                   | ((u64)pkhf2(v[2] + bias.z, v[3] + bias.w) << 32);
            E[pl * 16 + (cell ^ (pl & 7)) * 2 + half] = pk;
        }
    }
    const int pl4 = lane >> 2;
    const int dq  = lane & 3;
    ushort16* qn = qkv + (size_t)n * COUT * HW;
    #pragma unroll
    for (int s = 0; s < 2; ++s) {
        const int D = d0 + wm * 64 + s * 32;
        const int slot = D >> 5;
        ushort16* sb2 = qn + (size_t)slot * (HW * 32);
        #pragma unroll
        for (int g = 0; g < 4; ++g) {
            const int prow = g * 16 + pl4;
            const int c = s * 4 + dq;
            const uint4 val = *(const uint4*)&E[prow * 16 + ((c ^ (prow & 7)) * 2)];
            *(uint4*)(sb2 + (size_t)(p0 + wn * 64 + prow) * 32 + dq * 8) = val;
        }
    }
}

// ---------------------------------------------------------------------------
// Kernel 2 (v5): 5x5 neighborhood attention (best measured, ~19.6 us).
// LDS-staged K/V, XOR swizzle, packed math (fdot2 QK, pk_fma PV), DPP combine.
// ---------------------------------------------------------------------------
#define TR 4
#define TC 32
#define HR 8
#define HC 36
#define NPIX (HR*HC)  // 288

__global__ __launch_bounds__(256) void attn_kernel(
    const ushort16* __restrict__ qkv, float* __restrict__ out)
{
    __shared__ uint4 Ks[NPIX * 4];   // 18 KB
    __shared__ uint4 Vs[NPIX * 4];   // 18 KB

    const int n    = blockIdx.z;
    const int head = blockIdx.y;
    const int ht = blockIdx.x >> 1;
    const int wt = blockIdx.x & 1;
    const int h0 = ht * TR;
    const int w0 = wt * TC;

    const int tid  = threadIdx.x;
    const int half = tid & 1;
    const int wc   = (tid >> 1) & 31;
    const int tr   = tid >> 6;

    const int h = h0 + tr, w = w0 + wc;
    const int p = h * WW + w;

    const uint4* Kb = (const uint4*)(qkv + ((size_t)(n * 24 + 8 + head)) * HW * 32);
    const uint4* Vb = (const uint4*)(qkv + ((size_t)(n * 24 + 16 + head)) * HW * 32);

    for (int c = tid; c < 2 * NPIX * 4; c += 256) {
        const int b  = (c >= NPIX * 4);
        const int cc = c - b * NPIX * 4;
        const int pix = cc >> 2, i = cc & 3;
        const int hr = pix / HC, cw = pix - hr * HC;
        const int hh = h0 + hr - 2, ww = w0 + cw - 2;
        if (hh >= 0 && hh < HH && ww >= 0 && ww < WW) {
            const int pp = hh * WW + ww;
            const uint4 v = (b ? Vb : Kb)[(size_t)pp * 4 + i];
            const int unit = (pix * 4 + i) ^ (pix & 7);
            (b ? Vs : Ks)[unit] = v;
        }
    }

    hf2 q[8];
    {
        const uint4* Qp = (const uint4*)(qkv + (((size_t)(n * 24 + head)) * HW + p) * 32);
        union { uint4 u; hf2 h[4]; } c0, c1;
        c0.u = Qp[half * 2];
        c1.u = Qp[half * 2 + 1];
        #pragma unroll
        for (int i = 0; i < 4; ++i) { q[i] = c0.h[i]; q[4 + i] = c1.h[i]; }
    }

    __syncthreads();

    float sc[25];
    #pragma unroll
    for (int ky = 0; ky < 5; ++ky) {
        const int hh = h + ky - 2;
        const int hr = tr + ky;
        #pragma unroll
        for (int kx = 0; kx < 5; ++kx) {
            const int ww = w + kx - 2;
            float s;
            if (hh >= 0 && hh < HH && ww >= 0 && ww < WW) {
                const int pix = hr * HC + (wc + kx);
                const int u0 = (pix * 4 + half * 2)     ^ (pix & 7);
                const int u1 = (pix * 4 + half * 2 + 1) ^ (pix & 7);
                union { uint4 u; hf2 h[4]; } a, b;
                a.u = Ks[u0]; b.u = Ks[u1];
                float t = 0.f;
                t = dot2acc(q[0], a.h[0], t);
                t = dot2acc(q[1], a.h[1], t);
                t = dot2acc(q[2], a.h[2], t);
                t = dot2acc(q[3], a.h[3], t);
                t = dot2acc(q[4], b.h[0], t);
                t = dot2acc(q[5], b.h[1], t);
                t = dot2acc(q[6], b.h[2], t);
                t = dot2acc(q[7], b.h[3], t);
                s = t;
            } else {
                s = -1e30f;
            }
            sc[ky * 5 + kx] = s;
        }
    }
    #pragma unroll
    for (int k = 0; k < 25; ++k) {
        float o = dpp_xor1(sc[k]);
        sc[k] = (sc[k] <= -1e29f) ? sc[k] : sc[k] + o;
    }

    float m = sc[0];
    #pragma unroll
    for (int k = 1; k < 25; ++k) m = fmaxf(m, sc[k]);
    float sum = 0.f;
    #pragma unroll
    for (int k = 0; k < 25; ++k) {
        float e = __expf(sc[k] - m);
        sc[k] = e;
        sum += e;
    }
    const float inv = 1.f / sum;

    hf2 acch[8];
    #pragma unroll
    for (int i = 0; i < 8; ++i) acch[i] = (hf2){(_Float16)0.f, (_Float16)0.f};
    #pragma unroll
    for (int ky = 0; ky < 5; ++ky) {
        const int hh = h + ky - 2;
        if (hh < 0 || hh >= HH) continue;
        const int hr = tr + ky;
        #pragma unroll
        for (int kx = 0; kx < 5; ++kx) {
            const int ww = w + kx - 2;
            if (ww < 0 || ww >= WW) continue;
            const _Float16 af = (_Float16)sc[ky * 5 + kx];
            const hf2 ah = (hf2){af, af};
            const int pix = hr * HC + (wc + kx);
            const int u0 = (pix * 4 + half * 2)     ^ (pix & 7);
            const int u1 = (pix * 4 + half * 2 + 1) ^ (pix & 7);
            union { uint4 u; hf2 h[4]; } xv, yv;
            xv.u = Vs[u0]; yv.u = Vs[u1];
            acch[0] += ah * xv.h[0];
            acch[1] += ah * xv.h[1];
            acch[2] += ah * xv.h[2];
            acch[3] += ah * xv.h[3];
            acch[4] += ah * yv.h[0];
            acch[5] += ah * yv.h[1];
            acch[6] += ah * yv.h[2];
            acch[7] += ah * yv.h[3];
        }
    }

    float* Ob = out + ((size_t)(n * 8 + head) * 32 + half * 16) * HW + p;
    #pragma unroll
    for (int i = 0; i < 8; ++i) {
        Ob[(size_t)(2*i)   * HW] = (float)acch[i][0] * inv;
        Ob[(size_t)(2*i+1) * HW] = (float)acch[i][1] * inv;
    }
}

// ---------------------------------------------------------------------------
extern "C" void kernel_launch(void* const* d_in, const int* in_sizes, int n_in,
                              void* d_out, int out_size, void* d_ws, size_t ws_size,
                              hipStream_t stream) {
    const float* x  = (const float*)d_in[0];   // (4, 256, 64, 64)
    const float* wq = (const float*)d_in[1];   // (768, 256)
    const float* bq = (const float*)d_in[2];   // (768,)
    float* out = (float*)d_out;                // (4, 256, 64, 64) fp32
    ushort16* qkv = (ushort16*)d_ws;           // fp16 [4][24][4096][32] = 25 MB

    dim3 g1(HW / 128, COUT / 128, 4);          // (32, 6, 4) = 768 blocks
    qkv_gemm_kernel<<<g1, 256, 0, stream>>>(x, wq, bq, qkv);

    dim3 g2(32, 8, 4);
    attn_kernel<<<g2, 256, 0, stream>>>(qkv, out);
}